// Round 7
// baseline (105.199 us; speedup 1.0000x reference)
//
#include <hip/hip_runtime.h>
#include <math.h>

#define BB 32
#define TT 2048
#define DD 64
#define PRED 96
#define TP (TT + PRED)      // 2144
#define KTOP 8
#define MARGIN 8e-4f
#define PI_D 3.14159265358979323846
#define XT2_BYTES ((size_t)BB * 32 * TT * sizeof(float2))         // 16.78 MB
#define GCOEF_BYTES ((size_t)BB * DD * KTOP * sizeof(float4))     // 256 KB
#define WS_NEED (XT2_BYTES + GCOEF_BYTES)

// bit-reversal helpers/tables
__device__ __forceinline__ int br6(int l) { return (int)(__brev((unsigned)l) >> 26); }
static constexpr int BR3[8] = {0,4,2,6,1,5,3,7};
// cos/sin(2*pi*j/32), j=0..15 (compile-time twiddles; FFT-8 uses stride-4 idx)
static constexpr float C32T[16] = {
    1.0f, 0.98078528040323044913f, 0.92387953251128675613f, 0.83146961230254523708f,
    0.70710678118654752440f, 0.55557023301960222474f, 0.38268343236508977173f, 0.19509032201612826785f,
    0.0f, -0.19509032201612826785f, -0.38268343236508977173f, -0.55557023301960222474f,
    -0.70710678118654752440f, -0.83146961230254523708f, -0.92387953251128675613f, -0.98078528040323044913f};
static constexpr float S32T[16] = {
    0.0f, 0.19509032201612826785f, 0.38268343236508977173f, 0.55557023301960222474f,
    0.70710678118654752440f, 0.83146961230254523708f, 0.92387953251128675613f, 0.98078528040323044913f,
    1.0f, 0.98078528040323044913f, 0.92387953251128675613f, 0.83146961230254523708f,
    0.70710678118654752440f, 0.55557023301960222474f, 0.38268343236508977173f, 0.19509032201612826785f};

// * exp(-2*pi*i*m/2048) via 1-ulp HW trig (revolutions input, exact dyadic)
__device__ __forceinline__ float2 ctw(float2 a, int m) {
    const float rev = (float)m * (1.0f / 2048.0f);
    const float c = __builtin_amdgcn_cosf(rev);
    const float s = __builtin_amdgcn_sinf(rev);
    return make_float2(a.x * c + a.y * s, a.y * c - a.x * s);
}

// ---------------------------------------------------------------------------
// Transpose pre-kernel (verified in R6): x[b][t][d] -> xt2[b][dp][t]
// paired-complex. Fully coalesced on both sides.
// ---------------------------------------------------------------------------
__global__ __launch_bounds__(256) void transpose_kernel(const float* __restrict__ x,
                                                        float2* __restrict__ xt2) {
    __shared__ float tl[64 * 68];
    const int tid = threadIdx.x;
    const int bid = blockIdx.x;
    const int b   = bid >> 5;
    const int t0  = (bid & 31) * 64;

    const float4* xr = (const float4*)(x + ((size_t)b * TT + t0) * DD);
    {
        const int r = tid >> 2, c = tid & 3;
        #pragma unroll
        for (int j = 0; j < 4; ++j) {
            const float4 f = xr[r * 16 + c + 4 * j];
            *(float4*)&tl[r * 68 + (c + 4 * j) * 4] = f;
        }
    }
    __syncthreads();
    {
        const int dp = tid >> 3, c = tid & 7;
        float2* orow = xt2 + ((size_t)b * 32 + dp) * TT + t0;
        #pragma unroll
        for (int j = 0; j < 4; ++j) {
            const int t = 16 * j + 2 * c;
            float4 o;
            o.x = tl[t * 68 + 2 * dp];
            o.y = tl[t * 68 + 2 * dp + 1];
            o.z = tl[(t + 1) * 68 + 2 * dp];
            o.w = tl[(t + 1) * 68 + 2 * dp + 1];
            *(float4*)&orow[t] = o;
        }
    }
}

// POOL float layout (one signal-pair per block):
//   [0, 4608)     : cross-wave exchange, wv*1152 + p*18 + 2q
//   [4608, 8832)  : spectrum, a (re) / +2112 (im), a = k + (k>>5) skew
#define EXB(wvi,pi) ((wvi) * 1152 + (pi) * 18)
#define SRE(a) POOL[4608 + (a)]
#define SIM(a) POOL[6720 + (a)]

// ---------------------------------------------------------------------------
// Kernel A: FFT-2048 + selection, coefs -> gcoef[b*64+ch][k] = {fr, fi, k, 0}.
// 1024 blocks (b, dp). Waves 2,3 exit after the spectrum barrier; no trailing
// barrier (selection has no further __syncthreads -> early-exit safe).
// ---------------------------------------------------------------------------
__global__ __launch_bounds__(256, 2) void fft_select_kernel(const float2* __restrict__ xt2,
                                                            float4* __restrict__ gcoef) {
    __shared__ float POOL[8832];
    const int t    = threadIdx.x;
    const int wv   = t >> 6, p = t & 63;
    const int bid  = blockIdx.x;
    const int b    = bid >> 5;
    const int dp   = bid & 31;

    const float2* xp = xt2 + ((size_t)b * 32 + dp) * TT;
    const int br2wv = ((wv & 1) << 1) | ((wv >> 1) & 1);
    const int rl = 4 * br6(p) + br2wv;             // = br8(64*wv + p)

    float2 v[8];
    #pragma unroll
    for (int i = 0; i < 8; ++i)
        v[i] = xp[256 * BR3[i] + rl];

    // in-lane FFT-8
    #pragma unroll
    for (int s = 1; s <= 3; ++s) {
        const int m = 1 << s, half = m >> 1, stepw = 32 >> s;
        #pragma unroll
        for (int g = 0; g < 8; g += m) {
            #pragma unroll
            for (int j = 0; j < half; ++j) {
                const float c = C32T[j * stepw], sn = S32T[j * stepw];
                const int i0 = g + j, i1 = i0 + half;
                const float tr = c * v[i1].x + sn * v[i1].y;
                const float ti = c * v[i1].y - sn * v[i1].x;
                v[i1] = make_float2(v[i0].x - tr, v[i0].y - ti);
                v[i0] = make_float2(v[i0].x + tr, v[i0].y + ti);
            }
        }
    }
    #pragma unroll
    for (int q = 1; q < 8; ++q) v[q] = ctw(v[q], (rl * q) & (TT - 1));

    // cross-lane FFT-256 stages 1..6
    #pragma unroll
    for (int s = 1; s <= 6; ++s) {
        const int half = 1 << (s - 1);
        const float rev = (float)(p & (half - 1)) / (float)(1 << s);
        const float wc  = __builtin_amdgcn_cosf(rev);
        const float wsn = __builtin_amdgcn_sinf(rev);
        const bool  hi  = (p & half) != 0;
        #pragma unroll
        for (int q = 0; q < 8; ++q) {
            float2 pv;
            pv.x = __shfl_xor(v[q].x, half, 64);
            pv.y = __shfl_xor(v[q].y, half, 64);
            const float2 bsv = hi ? v[q] : pv;
            const float2 asv = hi ? pv : v[q];
            const float tr = wc * bsv.x + wsn * bsv.y;
            const float ti = wc * bsv.y - wsn * bsv.x;
            v[q] = hi ? make_float2(asv.x - tr, asv.y - ti)
                      : make_float2(asv.x + tr, asv.y + ti);
        }
    }

    // stage 7 (dist 64)
    {
        const int exw = EXB(wv, p);
        #pragma unroll
        for (int q = 0; q < 8; ++q) *(float2*)&POOL[exw + 2 * q] = v[q];
    }
    __syncthreads();
    {
        const int exr = EXB(wv ^ 1, p);
        const float rev7 = (float)p * (1.0f / 128.0f);
        const float c7 = __builtin_amdgcn_cosf(rev7);
        const float s7 = __builtin_amdgcn_sinf(rev7);
        const bool hi7 = (wv & 1) != 0;
        #pragma unroll
        for (int q = 0; q < 8; ++q) {
            const float2 pv = *(const float2*)&POOL[exr + 2 * q];
            const float2 bsv = hi7 ? v[q] : pv;
            const float2 asv = hi7 ? pv : v[q];
            const float tr = c7 * bsv.x + s7 * bsv.y;
            const float ti = c7 * bsv.y - s7 * bsv.x;
            v[q] = hi7 ? make_float2(asv.x - tr, asv.y - ti)
                       : make_float2(asv.x + tr, asv.y + ti);
        }
    }
    __syncthreads();

    // stage 8 (dist 128) + spectrum dump
    {
        const int exw = EXB(wv, p);
        #pragma unroll
        for (int q = 0; q < 8; ++q) *(float2*)&POOL[exw + 2 * q] = v[q];
    }
    __syncthreads();
    {
        const int exr = EXB(wv ^ 2, p);
        const float rev8 = (float)(64 * (wv & 1) + p) * (1.0f / 256.0f);
        const float c8 = __builtin_amdgcn_cosf(rev8);
        const float s8 = __builtin_amdgcn_sinf(rev8);
        const bool hi8 = ((wv >> 1) & 1) != 0;
        const int kb = 512 * wv + 8 * p;
        #pragma unroll
        for (int q = 0; q < 8; ++q) {
            const float2 pv = *(const float2*)&POOL[exr + 2 * q];
            const float2 bsv = hi8 ? v[q] : pv;
            const float2 asv = hi8 ? pv : v[q];
            const float tr = c8 * bsv.x + s8 * bsv.y;
            const float ti = c8 * bsv.y - s8 * bsv.x;
            const float re = hi8 ? (asv.x - tr) : (asv.x + tr);
            const float im = hi8 ? (asv.y - ti) : (asv.y + ti);
            const int k = kb + q, a = k + (k >> 5);
            SRE(a) = re;
            SIM(a) = im;
        }
    }
    __syncthreads();                               // full spectrum ready

    if (wv >= 2) return;                           // waves 2,3 done (no later barriers)

    // ======== selection: wave wv -> channel wv; 16 keys/lane ========
    const int w = wv;
    float4* gout = gcoef + ((size_t)b * DD + 2 * dp + w) * KTOP;
    unsigned A[16];
    #pragma unroll
    for (int q = 0; q < 16; ++q) {
        const int k = 16 * p + q;
        unsigned kk = 0u;
        if (k != 0) {
            const int a1 = k + (k >> 5);
            const int pk = TT - k, a2 = pk + (pk >> 5);
            const float zr = SRE(a1), zi = SIM(a1);
            const float yr = SRE(a2), yi = SIM(a2);
            float cr, ci;
            if (w == 0) { cr = 0.5f * (zr + yr); ci = 0.5f * (zi - yi); }
            else        { cr = 0.5f * (zi + yi); ci = 0.5f * (yr - zr); }
            const float mg = cr * cr + ci * ci;
            kk = (__float_as_uint(mg) & 0xFFFFF800u) | (unsigned)(2047 - k);
        }
        A[q] = kk;
    }
    // bitonic sort-16 descending
    #pragma unroll
    for (int sz = 2; sz <= 16; sz <<= 1) {
        #pragma unroll
        for (int d = sz >> 1; d > 0; d >>= 1) {
            #pragma unroll
            for (int i2 = 0; i2 < 16; ++i2) {
                const int j2i = i2 ^ d;
                if (j2i > i2) {
                    const bool desc = ((i2 & sz) == 0);
                    const unsigned a = A[i2], b2 = A[j2i];
                    const unsigned mx = a > b2 ? a : b2, mn = a > b2 ? b2 : a;
                    A[i2] = desc ? mx : mn;  A[j2i] = desc ? mn : mx;
                }
            }
        }
    }
    // 6 truncated XOR-merge stages
    #pragma unroll
    for (int off = 1; off <= 32; off <<= 1) {
        unsigned Bv[16];
        #pragma unroll
        for (int i2 = 0; i2 < 16; ++i2)
            Bv[i2] = (unsigned)__shfl_xor((int)A[i2], off, 64);
        #pragma unroll
        for (int i2 = 0; i2 < 16; ++i2) {
            const unsigned o = Bv[15 - i2];
            A[i2] = A[i2] > o ? A[i2] : o;
        }
        #pragma unroll
        for (int d = 8; d > 0; d >>= 1) {
            #pragma unroll
            for (int i2 = 0; i2 < 16; ++i2) {
                if ((i2 & d) == 0) {
                    const int j2i = i2 + d;
                    const unsigned a = A[i2], b2 = A[j2i];
                    A[i2] = a > b2 ? a : b2;  A[j2i] = a > b2 ? b2 : a;
                }
            }
        }
    }

    const float m8f = __uint_as_float(A[7] & 0xFFFFF800u);
    unsigned bandmask = 0u;
    #pragma unroll
    for (int r = 0; r < 16; ++r) {
        const float mr = __uint_as_float(A[r] & 0xFFFFF800u);
        if (fabsf(mr - m8f) <= MARGIN * m8f) bandmask |= (1u << r);
    }
    const int flg = (bandmask != (1u << 7)) ? 1 : 0;

    unsigned myk = 0u;
    #pragma unroll
    for (int i2 = 0; i2 < 16; ++i2) myk = (p == i2) ? A[i2] : myk;
    const int kcand = 2047 - (int)(myk & 0x7FFu);

    if (!flg && p < KTOP) {
        const int k = kcand, a1 = k + (k >> 5), pk = TT - k, a2 = pk + (pk >> 5);
        const float zr = SRE(a1), zi = SIM(a1);
        const float yr = SRE(a2), yi = SIM(a2);
        float cr, ci;
        if (w == 0) { cr = 0.5f * (zr + yr); ci = 0.5f * (zi - yi); }
        else        { cr = 0.5f * (zi + yi); ci = 0.5f * (yr - zr); }
        gout[p] = make_float4(cr * (2.0f / (float)TT), ci * (2.0f / (float)TT),
                              (float)k, 0.0f);
    }

    if (flg) {                                     // rare fp64 re-rank path
        float sv[32];
        #pragma unroll
        for (int m2 = 0; m2 < 32; ++m2) {
            const float2 s2 = xp[p + 64 * m2];
            sv[m2] = (w == 0) ? s2.x : s2.y;
        }
        const double thA = -2.0 * PI_D * (double)p / 64.0;
        const double thB = -2.0 * PI_D * (double)p / (double)TT;
        const double wac = cos(thA), was = sin(thA);
        const double wbc = cos(thB), wbs = sin(thB);

        const unsigned bm = bandmask;
        const int lo = (int)__builtin_ctz(bm);
        double myM = 0.0, myR = 0.0, myI = 0.0;
        for (int r = 0; r < 16; ++r) {
            if (!((bm >> r) & 1u)) continue;
            const int kr = __shfl(kcand, r, 64);
            double ar = 0.0, ai = 0.0;
            for (int m2 = 0; m2 < 32; ++m2) {
                const int n  = p + 64 * m2;
                const int mm = (n * kr) & (TT - 1);
                const double qc  = __shfl(wac, mm >> 5, 64);
                const double qs  = __shfl(was, mm >> 5, 64);
                const double rc2 = __shfl(wbc, mm & 31, 64);
                const double rs2 = __shfl(wbs, mm & 31, 64);
                const double wr = qc * rc2 - qs * rs2;
                const double wi = qc * rs2 + qs * rc2;
                ar = fma((double)sv[m2], wr, ar);
                ai = fma((double)sv[m2], wi, ai);
            }
            #pragma unroll
            for (int off = 32; off; off >>= 1) {
                ar += __shfl_xor(ar, off, 64);
                ai += __shfl_xor(ai, off, 64);
            }
            if (p == r) { myM = ar * ar + ai * ai; myR = ar; myI = ai; }
        }
        const int h16 = p & 15;
        const double selfM = __shfl(myM, h16, 64);
        const int    selfK = __shfl(kcand, h16, 64);
        int rb = 0;
        for (int r2 = 0; r2 < 16; ++r2) {
            if (!((bm >> r2) & 1u)) continue;
            const double om = __shfl(myM, r2, 64);
            const int    ok = __shfl(kcand, r2, 64);
            if (r2 != h16 && (om > selfM || (om == selfM && ok < selfK))) ++rb;
        }
        const int isband = (int)((bm >> h16) & 1u);
        const int rank = isband ? (lo + rb) : h16;
        if (p < 16 && rank < KTOP) {
            if (isband) {
                gout[rank] = make_float4((float)(myR * (2.0 / (double)TT)),
                                         (float)(myI * (2.0 / (double)TT)),
                                         (float)kcand, 0.0f);
            } else {
                const int k = kcand, a1 = k + (k >> 5), pk = TT - k, a2 = pk + (pk >> 5);
                const float zr = SRE(a1), zi = SIM(a1);
                const float yr = SRE(a2), yi = SIM(a2);
                float cr, ci;
                if (w == 0) { cr = 0.5f * (zr + yr); ci = 0.5f * (zi - yi); }
                else        { cr = 0.5f * (zi + yi); ci = 0.5f * (yr - zr); }
                gout[rank] = make_float4(cr * (2.0f / (float)TT),
                                         ci * (2.0f / (float)TT), (float)k, 0.0f);
            }
        }
    }
}

// ---------------------------------------------------------------------------
// Kernel B: synthesis. Block = one b x 67-row t-tile, all 64 channels.
// Thread (d = tid&63, tq = tid>>6): phasor rotation (stride 4) over its
// channel's 8 coefs into LDS tile TL[t][d]; cooperative float4 writeout
// (each wave stores 1 KB contiguous). Grid 32 b x 32 tiles = 1024 blocks.
// ---------------------------------------------------------------------------
__global__ __launch_bounds__(256, 4) void synth_kernel(const float4* __restrict__ gcoef,
                                                       float* __restrict__ out) {
    __shared__ float4 gcf[64 * 9];                 // [d][k] pad 9 (9.2 KB)
    __shared__ float  TL[67 * 64];                 // t-major tile (17.2 KB)
    const int tid = threadIdx.x;
    const int bid = blockIdx.x;
    const int b   = bid >> 5;
    const int t0  = (bid & 31) * 67;               // 32*67 = 2144 = TP

    // stage this b's 512 coef float4s, coalesced
    {
        const float4* gsrc = gcoef + (size_t)b * DD * KTOP;
        #pragma unroll
        for (int j = 0; j < 2; ++j) {
            const int i = tid + 256 * j;           // 0..511
            const float4 g = gsrc[i];
            gcf[(i >> 3) * 9 + (i & 7)] = g;
        }
    }
    __syncthreads();

    const int d = tid & 63, tq = tid >> 6;
    float fr[KTOP], fi[KTOP], pc[KTOP], ps[KTOP], rc[KTOP], rs[KTOP];
    #pragma unroll
    for (int k = 0; k < KTOP; ++k) {
        const float4 g = gcf[d * 9 + k];
        fr[k] = g.x; fi[k] = g.y;
        const int kc = (int)g.z;
        const int j0 = (kc * (t0 + tq)) & (TT - 1);
        pc[k] = __builtin_amdgcn_cosf((float)j0 * (1.0f / 2048.0f));
        ps[k] = __builtin_amdgcn_sinf((float)j0 * (1.0f / 2048.0f));
        const int jr = (kc * 4) & (TT - 1);
        rc[k] = __builtin_amdgcn_cosf((float)jr * (1.0f / 2048.0f));
        rs[k] = __builtin_amdgcn_sinf((float)jr * (1.0f / 2048.0f));
    }
    #pragma unroll 2
    for (int m = 0; m < 17; ++m) {                 // t = t0 + tq + 4m
        const int tloc = tq + 4 * m;
        float acc = 0.0f;
        #pragma unroll
        for (int k = 0; k < KTOP; ++k) acc += fr[k] * pc[k] - fi[k] * ps[k];
        if (tloc < 67) TL[tloc * 64 + d] = acc;    // banks: d&31, 2-way (free)
        #pragma unroll
        for (int k = 0; k < KTOP; ++k) {
            const float nc = pc[k] * rc[k] - ps[k] * rs[k];
            const float ns = pc[k] * rs[k] + ps[k] * rc[k];
            pc[k] = nc; ps[k] = ns;
        }
    }
    __syncthreads();

    // writeout: 67*64 = 4288 floats = 1072 float4; wave = 1 KB contiguous
    float* ob = out + ((size_t)b * TP + t0) * DD;
    #pragma unroll
    for (int it = 0; it < 5; ++it) {
        const int idx = it * 256 + tid;            // float4 index
        if (idx < 1072) {
            const int row = idx >> 4, q = idx & 15;
            *(float4*)&ob[(size_t)row * DD + 4 * q] = *(const float4*)&TL[row * 64 + 4 * q];
        }
    }
}

// ---------------------------------------------------------------------------
// Monolithic fallback (R6-verified, XT=false): used when d_ws is too small.
// ---------------------------------------------------------------------------
__global__ __launch_bounds__(256, 4) void mono_kernel(const float* __restrict__ x,
                                                      float* __restrict__ out) {
    __shared__ float POOL[8832];
    __shared__ int   coefK[2][KTOP];
    __shared__ float coefR[2][KTOP], coefI[2][KTOP];

    const int t    = threadIdx.x;
    const int wv   = t >> 6, p = t & 63;
    const int bid  = blockIdx.x;
    const int xcd  = bid & 7;
    const int idx  = bid >> 3;
    const int b    = ((idx >> 3) << 1) | (xcd >> 2);
    const int dp   = ((xcd & 3) << 3) | (idx & 7);

    const float2* xv = (const float2*)x;
    const size_t xbase = (size_t)b * TT * (DD / 2) + dp;
    const int br2wv = ((wv & 1) << 1) | ((wv >> 1) & 1);
    const int rl = 4 * br6(p) + br2wv;

    float2 v[8];
    #pragma unroll
    for (int i = 0; i < 8; ++i)
        v[i] = xv[xbase + (size_t)(256 * BR3[i] + rl) * (DD / 2)];

    #pragma unroll
    for (int s = 1; s <= 3; ++s) {
        const int m = 1 << s, half = m >> 1, stepw = 32 >> s;
        #pragma unroll
        for (int g = 0; g < 8; g += m) {
            #pragma unroll
            for (int j = 0; j < half; ++j) {
                const float c = C32T[j * stepw], sn = S32T[j * stepw];
                const int i0 = g + j, i1 = i0 + half;
                const float tr = c * v[i1].x + sn * v[i1].y;
                const float ti = c * v[i1].y - sn * v[i1].x;
                v[i1] = make_float2(v[i0].x - tr, v[i0].y - ti);
                v[i0] = make_float2(v[i0].x + tr, v[i0].y + ti);
            }
        }
    }
    #pragma unroll
    for (int q = 1; q < 8; ++q) v[q] = ctw(v[q], (rl * q) & (TT - 1));
    #pragma unroll
    for (int s = 1; s <= 6; ++s) {
        const int half = 1 << (s - 1);
        const float rev = (float)(p & (half - 1)) / (float)(1 << s);
        const float wc  = __builtin_amdgcn_cosf(rev);
        const float wsn = __builtin_amdgcn_sinf(rev);
        const bool  hi  = (p & half) != 0;
        #pragma unroll
        for (int q = 0; q < 8; ++q) {
            float2 pv;
            pv.x = __shfl_xor(v[q].x, half, 64);
            pv.y = __shfl_xor(v[q].y, half, 64);
            const float2 bsv = hi ? v[q] : pv;
            const float2 asv = hi ? pv : v[q];
            const float tr = wc * bsv.x + wsn * bsv.y;
            const float ti = wc * bsv.y - wsn * bsv.x;
            v[q] = hi ? make_float2(asv.x - tr, asv.y - ti)
                      : make_float2(asv.x + tr, asv.y + ti);
        }
    }
    {
        const int exw = EXB(wv, p);
        #pragma unroll
        for (int q = 0; q < 8; ++q) *(float2*)&POOL[exw + 2 * q] = v[q];
    }
    __syncthreads();
    {
        const int exr = EXB(wv ^ 1, p);
        const float rev7 = (float)p * (1.0f / 128.0f);
        const float c7 = __builtin_amdgcn_cosf(rev7);
        const float s7 = __builtin_amdgcn_sinf(rev7);
        const bool hi7 = (wv & 1) != 0;
        #pragma unroll
        for (int q = 0; q < 8; ++q) {
            const float2 pv = *(const float2*)&POOL[exr + 2 * q];
            const float2 bsv = hi7 ? v[q] : pv;
            const float2 asv = hi7 ? pv : v[q];
            const float tr = c7 * bsv.x + s7 * bsv.y;
            const float ti = c7 * bsv.y - s7 * bsv.x;
            v[q] = hi7 ? make_float2(asv.x - tr, asv.y - ti)
                       : make_float2(asv.x + tr, asv.y + ti);
        }
    }
    __syncthreads();
    {
        const int exw = EXB(wv, p);
        #pragma unroll
        for (int q = 0; q < 8; ++q) *(float2*)&POOL[exw + 2 * q] = v[q];
    }
    __syncthreads();
    {
        const int exr = EXB(wv ^ 2, p);
        const float rev8 = (float)(64 * (wv & 1) + p) * (1.0f / 256.0f);
        const float c8 = __builtin_amdgcn_cosf(rev8);
        const float s8 = __builtin_amdgcn_sinf(rev8);
        const bool hi8 = ((wv >> 1) & 1) != 0;
        const int kb = 512 * wv + 8 * p;
        #pragma unroll
        for (int q = 0; q < 8; ++q) {
            const float2 pv = *(const float2*)&POOL[exr + 2 * q];
            const float2 bsv = hi8 ? v[q] : pv;
            const float2 asv = hi8 ? pv : v[q];
            const float tr = c8 * bsv.x + s8 * bsv.y;
            const float ti = c8 * bsv.y - s8 * bsv.x;
            const float re = hi8 ? (asv.x - tr) : (asv.x + tr);
            const float im = hi8 ? (asv.y - ti) : (asv.y + ti);
            const int k = kb + q, a = k + (k >> 5);
            SRE(a) = re;
            SIM(a) = im;
        }
    }
    __syncthreads();

    if (wv < 2) {
        const int w = wv;
        unsigned A[16];
        #pragma unroll
        for (int q = 0; q < 16; ++q) {
            const int k = 16 * p + q;
            unsigned kk = 0u;
            if (k != 0) {
                const int a1 = k + (k >> 5);
                const int pk = TT - k, a2 = pk + (pk >> 5);
                const float zr = SRE(a1), zi = SIM(a1);
                const float yr = SRE(a2), yi = SIM(a2);
                float cr, ci;
                if (w == 0) { cr = 0.5f * (zr + yr); ci = 0.5f * (zi - yi); }
                else        { cr = 0.5f * (zi + yi); ci = 0.5f * (yr - zr); }
                const float mg = cr * cr + ci * ci;
                kk = (__float_as_uint(mg) & 0xFFFFF800u) | (unsigned)(2047 - k);
            }
            A[q] = kk;
        }
        #pragma unroll
        for (int sz = 2; sz <= 16; sz <<= 1) {
            #pragma unroll
            for (int d = sz >> 1; d > 0; d >>= 1) {
                #pragma unroll
                for (int i2 = 0; i2 < 16; ++i2) {
                    const int j2i = i2 ^ d;
                    if (j2i > i2) {
                        const bool desc = ((i2 & sz) == 0);
                        const unsigned a = A[i2], b2 = A[j2i];
                        const unsigned mx = a > b2 ? a : b2, mn = a > b2 ? b2 : a;
                        A[i2] = desc ? mx : mn;  A[j2i] = desc ? mn : mx;
                    }
                }
            }
        }
        #pragma unroll
        for (int off = 1; off <= 32; off <<= 1) {
            unsigned Bv[16];
            #pragma unroll
            for (int i2 = 0; i2 < 16; ++i2)
                Bv[i2] = (unsigned)__shfl_xor((int)A[i2], off, 64);
            #pragma unroll
            for (int i2 = 0; i2 < 16; ++i2) {
                const unsigned o = Bv[15 - i2];
                A[i2] = A[i2] > o ? A[i2] : o;
            }
            #pragma unroll
            for (int d = 8; d > 0; d >>= 1) {
                #pragma unroll
                for (int i2 = 0; i2 < 16; ++i2) {
                    if ((i2 & d) == 0) {
                        const int j2i = i2 + d;
                        const unsigned a = A[i2], b2 = A[j2i];
                        A[i2] = a > b2 ? a : b2;  A[j2i] = a > b2 ? b2 : a;
                    }
                }
            }
        }
        const float m8f = __uint_as_float(A[7] & 0xFFFFF800u);
        unsigned bandmask = 0u;
        #pragma unroll
        for (int r = 0; r < 16; ++r) {
            const float mr = __uint_as_float(A[r] & 0xFFFFF800u);
            if (fabsf(mr - m8f) <= MARGIN * m8f) bandmask |= (1u << r);
        }
        const int flg = (bandmask != (1u << 7)) ? 1 : 0;
        unsigned myk = 0u;
        #pragma unroll
        for (int i2 = 0; i2 < 16; ++i2) myk = (p == i2) ? A[i2] : myk;
        const int kcand = 2047 - (int)(myk & 0x7FFu);

        if (!flg && p < KTOP) {
            const int k = kcand, a1 = k + (k >> 5), pk = TT - k, a2 = pk + (pk >> 5);
            const float zr = SRE(a1), zi = SIM(a1);
            const float yr = SRE(a2), yi = SIM(a2);
            float cr, ci;
            if (w == 0) { cr = 0.5f * (zr + yr); ci = 0.5f * (zi - yi); }
            else        { cr = 0.5f * (zi + yi); ci = 0.5f * (yr - zr); }
            coefK[w][p] = k;
            coefR[w][p] = cr * (2.0f / (float)TT);
            coefI[w][p] = ci * (2.0f / (float)TT);
        }
        if (flg) {
            float sv[32];
            const float* xs = x + (size_t)b * TT * DD + 2 * dp + w;
            #pragma unroll
            for (int m2 = 0; m2 < 32; ++m2)
                sv[m2] = xs[(size_t)(p + 64 * m2) * DD];
            const double thA = -2.0 * PI_D * (double)p / 64.0;
            const double thB = -2.0 * PI_D * (double)p / (double)TT;
            const double wac = cos(thA), was = sin(thA);
            const double wbc = cos(thB), wbs = sin(thB);
            const unsigned bm = bandmask;
            const int lo = (int)__builtin_ctz(bm);
            double myM = 0.0, myR = 0.0, myI = 0.0;
            for (int r = 0; r < 16; ++r) {
                if (!((bm >> r) & 1u)) continue;
                const int kr = __shfl(kcand, r, 64);
                double ar = 0.0, ai = 0.0;
                for (int m2 = 0; m2 < 32; ++m2) {
                    const int n  = p + 64 * m2;
                    const int mm = (n * kr) & (TT - 1);
                    const double qc  = __shfl(wac, mm >> 5, 64);
                    const double qs  = __shfl(was, mm >> 5, 64);
                    const double rc2 = __shfl(wbc, mm & 31, 64);
                    const double rs2 = __shfl(wbs, mm & 31, 64);
                    const double wr = qc * rc2 - qs * rs2;
                    const double wi = qc * rs2 + qs * rc2;
                    ar = fma((double)sv[m2], wr, ar);
                    ai = fma((double)sv[m2], wi, ai);
                }
                #pragma unroll
                for (int off = 32; off; off >>= 1) {
                    ar += __shfl_xor(ar, off, 64);
                    ai += __shfl_xor(ai, off, 64);
                }
                if (p == r) { myM = ar * ar + ai * ai; myR = ar; myI = ai; }
            }
            const int h16 = p & 15;
            const double selfM = __shfl(myM, h16, 64);
            const int    selfK = __shfl(kcand, h16, 64);
            int rb = 0;
            for (int r2 = 0; r2 < 16; ++r2) {
                if (!((bm >> r2) & 1u)) continue;
                const double om = __shfl(myM, r2, 64);
                const int    ok = __shfl(kcand, r2, 64);
                if (r2 != h16 && (om > selfM || (om == selfM && ok < selfK))) ++rb;
            }
            const int isband = (int)((bm >> h16) & 1u);
            const int rank = isband ? (lo + rb) : h16;
            if (p < 16 && rank < KTOP) {
                coefK[w][rank] = kcand;
                if (isband) {
                    coefR[w][rank] = (float)(myR * (2.0 / (double)TT));
                    coefI[w][rank] = (float)(myI * (2.0 / (double)TT));
                } else {
                    const int k = kcand, a1 = k + (k >> 5), pk = TT - k, a2 = pk + (pk >> 5);
                    const float zr = SRE(a1), zi = SIM(a1);
                    const float yr = SRE(a2), yi = SIM(a2);
                    float cr, ci;
                    if (w == 0) { cr = 0.5f * (zr + yr); ci = 0.5f * (zi - yi); }
                    else        { cr = 0.5f * (zi + yi); ci = 0.5f * (yr - zr); }
                    coefR[w][rank] = cr * (2.0f / (float)TT);
                    coefI[w][rank] = ci * (2.0f / (float)TT);
                }
            }
        }
    }
    __syncthreads();

    const int d2 = t & 1, tq = t >> 1;
    float fr[KTOP], fi[KTOP], pc[KTOP], ps[KTOP], rc[KTOP], rs[KTOP];
    #pragma unroll
    for (int pp = 0; pp < KTOP; ++pp) {
        const int kc = coefK[d2][pp];
        fr[pp] = coefR[d2][pp];
        fi[pp] = coefI[d2][pp];
        const int j0 = (kc * tq) & (TT - 1);
        pc[pp] = __builtin_amdgcn_cosf((float)j0 * (1.0f / 2048.0f));
        ps[pp] = __builtin_amdgcn_sinf((float)j0 * (1.0f / 2048.0f));
        const int jr = (kc * 128) & (TT - 1);
        rc[pp] = __builtin_amdgcn_cosf((float)jr * (1.0f / 2048.0f));
        rs[pp] = __builtin_amdgcn_sinf((float)jr * (1.0f / 2048.0f));
    }
    float* ob = out + (size_t)b * TP * DD + 2 * dp + d2;
    #pragma unroll 2
    for (int m = 0; m < 17; ++m) {
        const int tv = tq + 128 * m;
        float acc = 0.0f;
        #pragma unroll
        for (int pp = 0; pp < KTOP; ++pp) acc += fr[pp] * pc[pp] - fi[pp] * ps[pp];
        if (tv < TP) ob[(size_t)tv * DD] = acc;
        #pragma unroll
        for (int pp = 0; pp < KTOP; ++pp) {
            const float nc = pc[pp] * rc[pp] - ps[pp] * rs[pp];
            const float ns = pc[pp] * rs[pp] + ps[pp] * rc[pp];
            pc[pp] = nc; ps[pp] = ns;
        }
    }
}

extern "C" void kernel_launch(void* const* d_in, const int* in_sizes, int n_in,
                              void* d_out, int out_size, void* d_ws, size_t ws_size,
                              hipStream_t stream) {
    const float* x = (const float*)d_in[0];
    float* out = (float*)d_out;
    (void)in_sizes; (void)n_in; (void)out_size;

    if (d_ws != nullptr && ws_size >= WS_NEED) {
        float2* xt2   = (float2*)d_ws;
        float4* gcoef = (float4*)((char*)d_ws + XT2_BYTES);
        transpose_kernel<<<BB * 32, 256, 0, stream>>>(x, xt2);
        fft_select_kernel<<<BB * 32, 256, 0, stream>>>(xt2, gcoef);
        synth_kernel<<<BB * 32, 256, 0, stream>>>(gcoef, out);
    } else {
        mono_kernel<<<BB * 32, 256, 0, stream>>>(x, out);
    }
}

// Round 8
// 93.591 us; speedup vs baseline: 1.1240x; 1.1240x over previous
//
#include <hip/hip_runtime.h>
#include <math.h>

#define BB 32
#define TT 2048
#define DD 64
#define PRED 96
#define TP (TT + PRED)      // 2144
#define KTOP 8
// Rare-path margin: must cover OUR fp32 FFT ranking error (~1e-6 rel), not
// more. 1e-4 keeps 50x safety while firing ~8x less often than 8e-4 ->
// cuts the fp64-DFT tail (~3-5 us) that sets the last-CU finish time.
#define MARGIN 1e-4f
#define PI_D 3.14159265358979323846

// bit-reversal helpers/tables
__device__ __forceinline__ int br6(int l) { return (int)(__brev((unsigned)l) >> 26); }
static constexpr int BR4[16] = {0,8,4,12,2,10,6,14,1,9,5,13,3,11,7,15};
// cos/sin(2*pi*j/32), j=0..15 (compile-time twiddles; FFT-16 uses even indices)
static constexpr float C32T[16] = {
    1.0f, 0.98078528040323044913f, 0.92387953251128675613f, 0.83146961230254523708f,
    0.70710678118654752440f, 0.55557023301960222474f, 0.38268343236508977173f, 0.19509032201612826785f,
    0.0f, -0.19509032201612826785f, -0.38268343236508977173f, -0.55557023301960222474f,
    -0.70710678118654752440f, -0.83146961230254523708f, -0.92387953251128675613f, -0.98078528040323044913f};
static constexpr float S32T[16] = {
    0.0f, 0.19509032201612826785f, 0.38268343236508977173f, 0.55557023301960222474f,
    0.70710678118654752440f, 0.83146961230254523708f, 0.92387953251128675613f, 0.98078528040323044913f,
    1.0f, 0.98078528040323044913f, 0.92387953251128675613f, 0.83146961230254523708f,
    0.70710678118654752440f, 0.55557023301960222474f, 0.38268343236508977173f, 0.19509032201612826785f};

// * exp(-2*pi*i*m/2048) via 1-ulp HW trig (revolutions input, exact dyadic)
__device__ __forceinline__ float2 ctw(float2 a, int m) {
    const float rev = (float)m * (1.0f / 2048.0f);
    const float c = __builtin_amdgcn_cosf(rev);
    const float s = __builtin_amdgcn_sinf(rev);
    return make_float2(a.x * c + a.y * s, a.y * c - a.x * s);
}

// POOL float layout:
//   [0, 9216)     : stage-7 cross-wave exchange, pair*4608 + w*2304 + p*36 + 4c
//                   (skew 36 keeps float4 alignment)
//   [9216, 17664) : spectra, pair*4224 + a (re) / +2112 (im), a = k + (k>>5) skew
#define SRE(pr,a) POOL[9216 + (pr) * 4224 + (a)]
#define SIM(pr,a) POOL[9216 + (pr) * 4224 + 2112 + (a)]

// ---------------------------------------------------------------------------
// 512 blocks x 256 threads (2 blocks/CU resident -> 2 waves/SIMD). This is
// the best-measured configuration (R1: 97.5 us). Each block: one batch b,
// 4 channels (2 packed signal-pairs). Each pair is FFT'd by TWO waves:
// in-lane FFT-16 x twiddle x cross-lane FFT-128 where stages 1..6 are
// in-wave shuffles and stage 7 (distance 64) is one LDS exchange. Lane
// bit-reversal folded into load addressing (rl = 2*br6(p)+w).
// Selection: one wave per channel (sort-16 + 6 truncated XOR merges).
// Synthesis writes directly to global (16B-grain stores via d4 layout).
// ---------------------------------------------------------------------------
__global__ __launch_bounds__(256, 2) void fused_kernel(const float* __restrict__ x,
                                                       float* __restrict__ out) {
    __shared__ float POOL[17664];                  // 70.7 KB
    __shared__ int   coefK[4][KTOP];
    __shared__ float coefR[4][KTOP], coefI[4][KTOP];

    const int t    = threadIdx.x;
    const int wv   = t >> 6, p = t & 63;
    const int pair = wv >> 1, w = wv & 1;          // pair 0..1, sig/half w 0..1
    // XCD swizzle: grp4 quads (one 64B output line) + input lines same XCD.
    const int bid  = blockIdx.x;
    const int xcd  = bid & 7;
    const int idx  = bid >> 3;                     // 0..63
    const int b    = (idx >> 3) * 4 + (xcd >> 1);  // 0..31
    const int grp4 = (xcd & 1) * 8 + (idx & 7);    // 0..15: 4-channel group
    const int dp   = grp4 * 2 + pair;              // float2 pair 0..31
    const int ch   = grp4 * 4 + wv;                // this wave's channel 0..63

    const float2* xv = (const float2*)x;
    const size_t xbase = (size_t)b * TT * (DD / 2) + dp;
    const int rl = 2 * br6(p) + w;                 // = br7(64*w + p)

    // ---- load: v[i] = x[n = 128*BR4[i] + rl] (both reversals folded in) ----
    float2 v[16];
    #pragma unroll
    for (int i = 0; i < 16; ++i)
        v[i] = xv[xbase + (size_t)(128 * BR4[i] + rl) * (DD / 2)];

    // ---- in-lane FFT-16 (DIT, natural-order output, constant twiddles) ----
    #pragma unroll
    for (int s = 1; s <= 4; ++s) {
        const int m = 1 << s, half = m >> 1, stepw = 32 >> s;
        #pragma unroll
        for (int g = 0; g < 16; g += m) {
            #pragma unroll
            for (int j = 0; j < half; ++j) {
                const float c = C32T[j * stepw], sn = S32T[j * stepw];
                const int i0 = g + j, i1 = i0 + half;
                const float tr = c * v[i1].x + sn * v[i1].y;
                const float ti = c * v[i1].y - sn * v[i1].x;
                v[i1] = make_float2(v[i0].x - tr, v[i0].y - ti);
                v[i0] = make_float2(v[i0].x + tr, v[i0].y + ti);
            }
        }
    }

    // ---- twiddle: v[q] *= W2048^(rl*q) (rl = subsequence index) ----
    #pragma unroll
    for (int q = 1; q < 16; ++q) v[q] = ctw(v[q], (rl * q) & (TT - 1));

    // ---- cross-lane FFT-128, stages 1..6 (in-wave xor shuffles) ----
    #pragma unroll
    for (int s = 1; s <= 6; ++s) {
        const int half = 1 << (s - 1);
        const float rev = (float)(p & (half - 1)) / (float)(1 << s);
        const float wc  = __builtin_amdgcn_cosf(rev);
        const float wsn = __builtin_amdgcn_sinf(rev);
        const bool  hi  = (p & half) != 0;
        #pragma unroll
        for (int q = 0; q < 16; ++q) {
            float2 pv;
            pv.x = __shfl_xor(v[q].x, half, 64);
            pv.y = __shfl_xor(v[q].y, half, 64);
            const float2 bsv = hi ? v[q] : pv;
            const float2 asv = hi ? pv : v[q];
            const float tr = wc * bsv.x + wsn * bsv.y;
            const float ti = wc * bsv.y - wsn * bsv.x;
            v[q] = hi ? make_float2(asv.x - tr, asv.y - ti)
                      : make_float2(asv.x + tr, asv.y + ti);
        }
    }

    // ---- stage 7 (distance 64 = cross-wave) via LDS + fused spectrum dump --
    {
        const int exw = pair * 4608 + w * 2304 + p * 36;
        #pragma unroll
        for (int c = 0; c < 8; ++c)
            *(float4*)&POOL[exw + 4 * c] =
                make_float4(v[2*c].x, v[2*c].y, v[2*c+1].x, v[2*c+1].y);
    }
    __syncthreads();                               // partner's half visible
    {
        const int exr = pair * 4608 + (1 - w) * 2304 + p * 36;
        const float revp = (float)p * (1.0f / 128.0f);
        const float wc7 = __builtin_amdgcn_cosf(revp);
        const float ws7 = __builtin_amdgcn_sinf(revp);
        const int kb = 1024 * w + 16 * p;          // this lane's k base
        #pragma unroll
        for (int c = 0; c < 8; ++c) {
            const float4 g = *(const float4*)&POOL[exr + 4 * c];
            #pragma unroll
            for (int e = 0; e < 2; ++e) {
                const int q = 2 * c + e;
                const float2 pv = e ? make_float2(g.z, g.w) : make_float2(g.x, g.y);
                const float2 bsv = w ? v[q] : pv;  // hi-half (w=1) operand
                const float2 asv = w ? pv : v[q];
                const float tr = wc7 * bsv.x + ws7 * bsv.y;
                const float ti = wc7 * bsv.y - ws7 * bsv.x;
                const int k = kb + q, a = k + (k >> 5);
                SRE(pair, a) = w ? (asv.x - tr) : (asv.x + tr);
                SIM(pair, a) = w ? (asv.y - ti) : (asv.y + ti);
            }
        }
    }
    __syncthreads();                               // full pair spectrum ready

    // ======== selection: one wave per channel, 16 keys/lane ========
    unsigned A[16];
    #pragma unroll
    for (int q = 0; q < 16; ++q) {
        const int k = 16 * p + q;                  // 0..1023
        unsigned kk = 0u;
        if (k != 0) {
            const int a1 = k + (k >> 5);
            const int pk = TT - k, a2 = pk + (pk >> 5);
            const float zr = SRE(pair, a1), zi = SIM(pair, a1);
            const float yr = SRE(pair, a2), yi = SIM(pair, a2);
            float cr, ci;
            if (w == 0) { cr = 0.5f * (zr + yr); ci = 0.5f * (zi - yi); }
            else        { cr = 0.5f * (zi + yi); ci = 0.5f * (yr - zr); }
            const float mg = cr * cr + ci * ci;
            kk = (__float_as_uint(mg) & 0xFFFFF800u) | (unsigned)(2047 - k);
        }
        A[q] = kk;
    }

    // in-register bitonic sort-16, descending
    #pragma unroll
    for (int sz = 2; sz <= 16; sz <<= 1) {
        #pragma unroll
        for (int d = sz >> 1; d > 0; d >>= 1) {
            #pragma unroll
            for (int i2 = 0; i2 < 16; ++i2) {
                const int j2i = i2 ^ d;
                if (j2i > i2) {
                    const bool desc = ((i2 & sz) == 0);
                    const unsigned a = A[i2], b2 = A[j2i];
                    const unsigned mx = a > b2 ? a : b2, mn = a > b2 ? b2 : a;
                    A[i2] = desc ? mx : mn;  A[j2i] = desc ? mn : mx;
                }
            }
        }
    }
    // 6 truncated XOR-merge stages across 64 lanes -> global top-16
    #pragma unroll
    for (int off = 1; off <= 32; off <<= 1) {
        unsigned Bv[16];
        #pragma unroll
        for (int i2 = 0; i2 < 16; ++i2)
            Bv[i2] = (unsigned)__shfl_xor((int)A[i2], off, 64);
        #pragma unroll
        for (int i2 = 0; i2 < 16; ++i2) {
            const unsigned o = Bv[15 - i2];
            A[i2] = A[i2] > o ? A[i2] : o;         // top-16 multiset, bitonic
        }
        #pragma unroll
        for (int d = 8; d > 0; d >>= 1) {
            #pragma unroll
            for (int i2 = 0; i2 < 16; ++i2) {
                if ((i2 & d) == 0) {
                    const int j2i = i2 + d;
                    const unsigned a = A[i2], b2 = A[j2i];
                    A[i2] = a > b2 ? a : b2;  A[j2i] = a > b2 ? b2 : a;
                }
            }
        }
    }
    // every lane: sorted top-16 of this wave's channel

    const float m8f = __uint_as_float(A[7] & 0xFFFFF800u);
    unsigned bandmask = 0u;
    #pragma unroll
    for (int r = 0; r < 16; ++r) {
        const float mr = __uint_as_float(A[r] & 0xFFFFF800u);
        if (fabsf(mr - m8f) <= MARGIN * m8f) bandmask |= (1u << r);
    }
    const int flg = (bandmask != (1u << 7)) ? 1 : 0;   // wave-uniform

    unsigned myk = 0u;                                 // candidate p (p<16)
    #pragma unroll
    for (int i2 = 0; i2 < 16; ++i2) myk = (p == i2) ? A[i2] : myk;
    const int kcand = 2047 - (int)(myk & 0x7FFu);

    if (!flg && p < KTOP) {
        const int k = kcand, a1 = k + (k >> 5), pk = TT - k, a2 = pk + (pk >> 5);
        const float zr = SRE(pair, a1), zi = SIM(pair, a1);
        const float yr = SRE(pair, a2), yi = SIM(pair, a2);
        float cr, ci;
        if (w == 0) { cr = 0.5f * (zr + yr); ci = 0.5f * (zi - yi); }
        else        { cr = 0.5f * (zi + yi); ci = 0.5f * (yr - zr); }
        coefK[wv][p] = k;
        coefR[wv][p] = cr * (2.0f / (float)TT);
        coefI[wv][p] = ci * (2.0f / (float)TT);
    }

    // ---- rare path: fp64 DFT of band members, exact re-rank + splice ----
    if (flg) {
        float sv[32];
        const float* xs = x + (size_t)b * TT * DD + ch;
        #pragma unroll
        for (int m2 = 0; m2 < 32; ++m2)
            sv[m2] = xs[(size_t)(p + 64 * m2) * DD];
        const double thA = -2.0 * PI_D * (double)p / 64.0;
        const double thB = -2.0 * PI_D * (double)p / (double)TT;
        const double wac = cos(thA), was = sin(thA);
        const double wbc = cos(thB), wbs = sin(thB);

        const unsigned bm = bandmask;              // uniform across wave
        const int lo = (int)__builtin_ctz(bm);
        double myM = 0.0, myR = 0.0, myI = 0.0;
        for (int r = 0; r < 16; ++r) {
            if (!((bm >> r) & 1u)) continue;       // wave-uniform
            const int kr = __shfl(kcand, r, 64);
            double ar = 0.0, ai = 0.0;
            for (int m2 = 0; m2 < 32; ++m2) {
                const int n  = p + 64 * m2;
                const int mm = (n * kr) & (TT - 1);
                const double qc  = __shfl(wac, mm >> 5, 64);
                const double qs  = __shfl(was, mm >> 5, 64);
                const double rc2 = __shfl(wbc, mm & 31, 64);
                const double rs2 = __shfl(wbs, mm & 31, 64);
                const double wr = qc * rc2 - qs * rs2;
                const double wi = qc * rs2 + qs * rc2;
                ar = fma((double)sv[m2], wr, ar);
                ai = fma((double)sv[m2], wi, ai);
            }
            #pragma unroll
            for (int off = 32; off; off >>= 1) {
                ar += __shfl_xor(ar, off, 64);
                ai += __shfl_xor(ai, off, 64);
            }
            if (p == r) { myM = ar * ar + ai * ai; myR = ar; myI = ai; }
        }
        // rank on ALL lanes (shuffles fully active), write on lanes < 16
        const int h16 = p & 15;
        const double selfM = __shfl(myM, h16, 64);
        const int    selfK = __shfl(kcand, h16, 64);
        int rb = 0;
        for (int r2 = 0; r2 < 16; ++r2) {
            if (!((bm >> r2) & 1u)) continue;
            const double om = __shfl(myM, r2, 64);
            const int    ok = __shfl(kcand, r2, 64);
            if (r2 != h16 && (om > selfM || (om == selfM && ok < selfK))) ++rb;
        }
        const int isband = (int)((bm >> h16) & 1u);
        const int rank = isband ? (lo + rb) : h16;
        if (p < 16 && rank < KTOP) {
            coefK[wv][rank] = kcand;
            if (isband) {
                coefR[wv][rank] = (float)(myR * (2.0 / (double)TT));
                coefI[wv][rank] = (float)(myI * (2.0 / (double)TT));
            } else {
                const int k = kcand, a1 = k + (k >> 5), pk = TT - k, a2 = pk + (pk >> 5);
                const float zr = SRE(pair, a1), zi = SIM(pair, a1);
                const float yr = SRE(pair, a2), yi = SIM(pair, a2);
                float cr, ci;
                if (w == 0) { cr = 0.5f * (zr + yr); ci = 0.5f * (zi - yi); }
                else        { cr = 0.5f * (zi + yi); ci = 0.5f * (yr - zr); }
                coefR[wv][rank] = cr * (2.0f / (float)TT);
                coefI[wv][rank] = ci * (2.0f / (float)TT);
            }
        }
    }
    __syncthreads();   // all 4 channels' coefs ready

    // ======== synthesis: phasor rotation, DIRECT global stores ========
    // thread -> (d4 = t&3, tq = t>>2 in [0,64)); tv = tq + 64*m, m = 0..33
    const int d4 = t & 3, tq = t >> 2;
    int   kc[KTOP];
    float fr[KTOP], fi[KTOP], pc[KTOP], ps[KTOP], rc[KTOP], rs[KTOP];
    #pragma unroll
    for (int pp = 0; pp < KTOP; ++pp) {
        kc[pp] = coefK[d4][pp];
        fr[pp] = coefR[d4][pp];
        fi[pp] = coefI[d4][pp];
        const int j0 = (kc[pp] * tq) & (TT - 1);
        const float rv0 = (float)j0 * (1.0f / 2048.0f);
        pc[pp] = __builtin_amdgcn_cosf(rv0);
        ps[pp] = __builtin_amdgcn_sinf(rv0);
        const int jr = (kc[pp] * 64) & (TT - 1);
        const float rvr = (float)jr * (1.0f / 2048.0f);
        rc[pp] = __builtin_amdgcn_cosf(rvr);
        rs[pp] = __builtin_amdgcn_sinf(rvr);
    }
    float* ob = out + (size_t)b * TP * DD + grp4 * 4 + d4;
    #pragma unroll 2
    for (int m = 0; m < 34; ++m) {                 // 33*64 + 32 = 2144 = TP
        const int tv = tq + 64 * m;
        float acc = 0.0f;
        #pragma unroll
        for (int pp = 0; pp < KTOP; ++pp) acc += fr[pp] * pc[pp] - fi[pp] * ps[pp];
        if (tv < TP) ob[(size_t)tv * DD] = acc;
        #pragma unroll
        for (int pp = 0; pp < KTOP; ++pp) {
            const float nc = pc[pp] * rc[pp] - ps[pp] * rs[pp];
            const float ns = pc[pp] * rs[pp] + ps[pp] * rc[pp];
            pc[pp] = nc; ps[pp] = ns;
        }
    }
}

extern "C" void kernel_launch(void* const* d_in, const int* in_sizes, int n_in,
                              void* d_out, int out_size, void* d_ws, size_t ws_size,
                              hipStream_t stream) {
    const float* x = (const float*)d_in[0];
    float* out = (float*)d_out;
    (void)d_ws; (void)ws_size; (void)in_sizes; (void)n_in; (void)out_size;

    fused_kernel<<<BB * 16, 256, 0, stream>>>(x, out);
}